// Round 14
// baseline (548.149 us; speedup 1.0000x reference)
//
#include <hip/hip_runtime.h>
#include <hip/hip_bf16.h>

// R30: MFMA dense path. R24-R29 established: gather9 72.5us/layer structural,
// scatter@512 best (below 72.5 vs 77 @256), preprocessing variants in ±10us
// noise, totals 535-547. MfmaUtil was 0 all session: the 3 GEMMs (~100-150us
// combined, VALU-FMA bound) never used matrix cores. R30 rewrites gemm1 +
// gemm64<RELU,AGG> with mfma_f32_16x16x32_bf16 (verified layouts: C/D
// col=lane&15,row=(lane>>4)*4+reg; A row=lane&15,k=8*(lane>>4)+i; B symm).
// Numerics: BN folded into W (W''=sc*W bf16, fold-bias sh^T*W f32) so the
// A operand is the EXACT raw bf16 tensor (relu exact on bf16); only W gets
// ~2^-9 rounding -> ~0.002 output delta (current absmax 0.0156). LDS W
// stored transposed + chunk-XOR swizzle (stride-128/256B rows are 16-way
// bank conflicts; swizzle -> 2-way = free). Everything else = R29 + R27's
// scatter@512.

#define NN 100000
#define NE 3200000
#define INV_N (1.0f/100000.0f)
#define BN_EPS 1e-5f
#define NBK 782            // buckets of 128 nodes
#define NSB 512            // scatter/hist blocks
#define EPB 6250           // edges per scatter/hist block (NSB*EPB == NE)
#define CAPB 6144          // LDS staging per bucket (mean 4092 + 32 sigma)
#define QBLK8 6250         // gather blocks per half (4 waves x 4 nodes)
#define HQW (NN*8)         // uint2 per half-table

typedef __attribute__((ext_vector_type(8))) short short8v;
typedef __attribute__((ext_vector_type(4))) float f32x4;
union U8 { uint4 q; short8v v; };

static __device__ __forceinline__ float bf2f(unsigned short u) {
    if ((u & 0x7f80u) == 0x7f80u) u = 0;          // inf/NaN -> 0 (input scrub)
    union { unsigned int i; float f; } z; z.i = ((unsigned int)u) << 16; return z.f;
}
static __device__ __forceinline__ float scrubf(float v) {
    return (fabsf(v) < 1e30f) ? v : 0.f;
}
static __device__ __forceinline__ unsigned short f2bf(float v) {
    union { float f; unsigned int i; } z; z.f = v;
    unsigned int lsb = (z.i >> 16) & 1u; z.i += 0x7fffu + lsb;
    return (unsigned short)(z.i >> 16);
}
static __device__ __forceinline__ float ld1(const void* p, size_t i, int f) {
    return f ? scrubf(((const float*)p)[i]) : bf2f(((const unsigned short*)p)[i]);
}
static __device__ __forceinline__ float4 ld4(const void* p, size_t g, int f) {
    if (f) { float4 v = ((const float4*)p)[g];
             return make_float4(scrubf(v.x),scrubf(v.y),scrubf(v.z),scrubf(v.w)); }
    ushort4 u = ((const ushort4*)p)[g];
    return make_float4(bf2f(u.x),bf2f(u.y),bf2f(u.z),bf2f(u.w));
}
static __device__ __forceinline__ int getidx(const int* ei, size_t pos, int i64) {
    return i64 ? ei[2*pos] : ei[pos];
}
static __device__ __forceinline__ float blo(unsigned v) {
    union { unsigned u; float f; } z; z.u = v << 16; return z.f;
}
static __device__ __forceinline__ float bhi(unsigned v) {
    union { unsigned u; float f; } z; z.u = v & 0xffff0000u; return z.f;
}
static __device__ __forceinline__ unsigned w15of(unsigned wu) {
    unsigned lsb = (wu >> 17) & 1u;
    return ((wu + 0xFFFFu + lsb) >> 17) & 0x7fffu;
}
static __device__ __forceinline__ unsigned scrub2(unsigned u) {
    unsigned lo = u & 0xffffu, hi = u >> 16;
    if ((lo & 0x7f80u) == 0x7f80u) lo = 0;
    if ((hi & 0x7f80u) == 0x7f80u) hi = 0;
    return lo | (hi << 16);
}
static __device__ __forceinline__ unsigned relu2(unsigned u) {
    unsigned lo = u & 0xffffu, hi = u >> 16;
    if ((lo & 0x7f80u) == 0x7f80u || (lo & 0x8000u)) lo = 0;
    if ((hi & 0x7f80u) == 0x7f80u || (hi & 0x8000u)) hi = 0;
    return lo | (hi << 16);
}
static __device__ __forceinline__ unsigned pkf(float a, float b) {
    return (unsigned)f2bf(a) | ((unsigned)f2bf(b) << 16);
}
// LDS swizzles: XOR the 8-elem chunk index with low col bits (2-way residual)
static __device__ __forceinline__ int sw1(int col, int k) {      // K=128
    return col*128 + ((k & ~7) ^ ((col & 15) << 3)) + (k & 7);
}
static __device__ __forceinline__ int sw2(int col, int k) {      // K=64
    return col*64 + ((k & ~7) ^ ((col & 7) << 3)) + (k & 7);
}

// ---------------- detector + sums zero ----------------
__global__ void k_detect2(const unsigned short* __restrict__ x,
                          const int* __restrict__ ei, int* __restrict__ flag,
                          float* __restrict__ sums) {
    __shared__ int cnt[256];
    int tid = threadIdx.x, c = 0;
    for (int i = tid; i < 1024; i += 256) {
        unsigned short u = x[i];
        int ex = (u >> 7) & 0xff;
        if ((u & 0x7fffu) != 0 && (ex >= 0xB0 || ex <= 0x40)) c++;
    }
    cnt[tid] = c; __syncthreads();
    if (tid == 0) { int t = 0; for (int i = 0; i < 256; ++i) t += cnt[i];
                    flag[0] = (t > 64) ? 1 : 0; }
    if (tid == 1) { int nz = 0; for (int i = 1; i < 64; i += 2) nz |= ei[i];
                    flag[1] = (nz == 0) ? 1 : 0; }
    if (tid < 128) { sums[tid]=0.f; sums[128+tid]=0.f; sums[256+tid]=0.f; }
}

// ================= bucket counting sort (no global atomics) =================

__global__ __launch_bounds__(256) void k_hist(const int* __restrict__ flag,
                                              const int* __restrict__ ei,
                                              int* __restrict__ histmat) {
    __shared__ int hh[NBK];
    const int i64 = flag[1];
    const int blk = blockIdx.x, tid = threadIdx.x;
    for (int b = tid; b < NBK; b += 256) hh[b] = 0;
    __syncthreads();
    const size_t e0 = (size_t)blk * EPB;
    for (int e = tid; e < EPB; e += 256) {
        unsigned d = (unsigned)getidx(ei, NE + e0 + e, i64);
        if (d < NN) atomicAdd(&hh[d >> 7], 1);
    }
    __syncthreads();
    for (int b = tid; b < NBK; b += 256) histmat[blk*NBK + b] = hh[b];
}

__global__ __launch_bounds__(256) void k_scanA(int* __restrict__ histmat,
                                               int* __restrict__ btot) {
    __shared__ int sd[256];
    const int b = blockIdx.x, t = threadIdx.x;
    int v0 = histmat[(2*t)*NBK + b];
    int v1 = histmat[(2*t+1)*NBK + b];
    int ts = v0 + v1;
    sd[t] = ts; __syncthreads();
    #pragma unroll
    for (int ofs = 1; ofs < 256; ofs <<= 1) {
        int a = (t >= ofs) ? sd[t-ofs] : 0;
        __syncthreads(); sd[t] += a; __syncthreads();
    }
    int excl = sd[t] - ts;
    histmat[(2*t)*NBK + b]   = excl;
    histmat[(2*t+1)*NBK + b] = excl + v0;
    if (t == 255) btot[b] = sd[255];
}

__global__ void k_scanB(const int* __restrict__ btot, int* __restrict__ bstart,
                        unsigned* __restrict__ edata) {
    __shared__ int sd[1024];
    int t = threadIdx.x;
    int v = (t < NBK) ? btot[t] : 0;
    sd[t] = v; __syncthreads();
    #pragma unroll
    for (int ofs = 1; ofs < 1024; ofs <<= 1) {
        int a = (t >= ofs) ? sd[t-ofs] : 0;
        __syncthreads(); sd[t] += a; __syncthreads();
    }
    if (t <= NBK) bstart[t] = sd[t] - v;
    if (t < 64) edata[(int)t - 64] = 0u;   // pad: w15=0 -> coef +0.0
}

__global__ __launch_bounds__(512) void k_scatter(
    const int* __restrict__ flag, const int* __restrict__ ei,
    const void* __restrict__ ew, const int* __restrict__ histmat,
    const int* __restrict__ bstart, int2* __restrict__ scr) {
    __shared__ int cursor[NBK];
    const int f = flag[0], i64 = flag[1];
    const int blk = blockIdx.x, tid = threadIdx.x;
    for (int b = tid; b < NBK; b += 512)
        cursor[b] = histmat[blk*NBK + b] + bstart[b];
    __syncthreads();
    const size_t e0 = (size_t)blk * EPB;
    for (int e = tid; e < EPB; e += 512) {
        unsigned d = (unsigned)getidx(ei, NE + e0 + e, i64);
        if (d >= NN) continue;
        unsigned s = (unsigned)getidx(ei, e0 + e, i64);
        float w = ld1(ew, e0 + e, f);
        if (s >= NN) { s = 0; w = 0.f; }
        int pos = atomicAdd(&cursor[d >> 7], 1);
        scr[pos] = make_int2((int)(((d & 127u) << 17) | s), __float_as_int(w));
    }
}

__global__ __launch_bounds__(256) void k_sortdeg(
    const int* __restrict__ bstart, const int2* __restrict__ scr,
    unsigned* __restrict__ edata, int* __restrict__ rowptr, float* __restrict__ dis) {
    __shared__ unsigned sp[CAPB];
    __shared__ unsigned out[CAPB];
    __shared__ unsigned short sww[CAPB];
    __shared__ int cnt[128], scn[128], cur[128];
    __shared__ float degf[128];
    const int b = blockIdx.x, tid = threadIdx.x;
    const int node0 = b * 128;
    const int r0 = bstart[b], r1 = bstart[b+1], n = r1 - r0;
    const bool fit = (n <= CAPB);

    if (tid < 128) { cnt[tid] = 0; degf[tid] = 1.0f; }
    __syncthreads();
    if (fit) {
        for (int j = tid; j < n; j += 256) {
            int2 m = scr[r0 + j];
            sp[j] = (unsigned)m.x;
            sww[j] = (unsigned short)w15of((unsigned)m.y);
            int l = (m.x >> 17) & 127;
            atomicAdd(&cnt[l], 1);
            atomicAdd(&degf[l], __int_as_float(m.y));
        }
    } else {
        for (int j = tid; j < n; j += 256) {
            int2 m = scr[r0 + j];
            int l = (m.x >> 17) & 127;
            atomicAdd(&cnt[l], 1);
            atomicAdd(&degf[l], __int_as_float(m.y));
        }
    }
    __syncthreads();
    if (tid < 128) scn[tid] = cnt[tid];
    __syncthreads();
    #pragma unroll
    for (int ofs = 1; ofs < 128; ofs <<= 1) {
        int a = 0;
        if (tid < 128 && tid >= ofs) a = scn[tid - ofs];
        __syncthreads();
        if (tid < 128) scn[tid] += a;
        __syncthreads();
    }
    if (tid < 128) {
        int excl = scn[tid] - cnt[tid];
        cur[tid] = excl;
        int node = node0 + tid;
        if (node <= NN) rowptr[node] = r0 + excl;
        if (node <  NN) dis[node] = rsqrtf(fmaxf(degf[tid], 1e-12f));
    }
    __syncthreads();
    if (fit) {
        for (int j = tid; j < n; j += 256) {
            unsigned p = sp[j];
            int l = (p >> 17) & 127;
            int pos = atomicAdd(&cur[l], 1);
            out[pos] = (p & 0x1ffffu) | ((unsigned)sww[j] << 17);
        }
        __syncthreads();
        for (int j = tid; j < n; j += 256)
            edata[r0 + j] = out[j];
    } else {
        for (int j = tid; j < n; j += 256) {
            int2 m = scr[r0 + j];
            int l = (m.x >> 17) & 127;
            int pos = atomicAdd(&cur[l], 1);
            edata[r0 + pos] = ((unsigned)m.x & 0x1ffffu) | (w15of((unsigned)m.y) << 17);
        }
    }
}

// gather (unchanged from R24/R29): half-split, 2-deep pipeline, zero-pad clamp
__global__ __launch_bounds__(256, 4) void k_gather9(
    const int* __restrict__ flag, const int* __restrict__ rowptr,
    const unsigned* __restrict__ edata, const float* __restrict__ dis,
    const void* __restrict__ bias, const uint2* __restrict__ hq,
    uint2* __restrict__ aggB) {
    const int f = flag[0];
    const int half = blockIdx.x / QBLK8;
    const int bq   = blockIdx.x % QBLK8;
    const int node0 = bq * 16 + (threadIdx.x >> 6) * 4;
    const int lane = threadIdx.x & 63;
    const int g = lane >> 3;
    const unsigned l = (unsigned)(lane & 7);
    const uint2* __restrict__ hb = hq + (size_t)half * HQW;

    const int r0 = rowptr[node0+0], r1 = rowptr[node0+1];
    const int r2 = rowptr[node0+2], r3 = rowptr[node0+3];
    const int r4 = rowptr[node0+4];
    const float d0 = dis[node0+0], d1 = dis[node0+1];
    const float d2v = dis[node0+2], d3 = dis[node0+3];

    int mx = max(max(r1-r0, r2-r1), max(r3-r2, r4-r3));
    const int nsteps = (mx + 7) >> 3;

    float a00=0,a01=0,a02=0,a03=0;
    float a10=0,a11=0,a12=0,a13=0;
    float a20=0,a21=0,a22=0,a23=0;
    float a30=0,a31=0,a32=0,a33=0;

    int ia0 = r0 + g, ia1 = r1 + g, ia2 = r2 + g, ia3 = r3 + g;
    unsigned m0 = edata[ia0 < r1 ? ia0 : -64];
    unsigned m1 = edata[ia1 < r2 ? ia1 : -64];
    unsigned m2 = edata[ia2 < r3 ? ia2 : -64];
    unsigned m3 = edata[ia3 < r4 ? ia3 : -64];
    uint2 w0 = hb[(m0 & 0x1ffffu)*8u + l];
    uint2 w1 = hb[(m1 & 0x1ffffu)*8u + l];
    uint2 w2 = hb[(m2 & 0x1ffffu)*8u + l];
    uint2 w3 = hb[(m3 & 0x1ffffu)*8u + l];
    float c0 = __int_as_float((int)(m0 & 0xFFFE0000u)) * d0;
    float c1 = __int_as_float((int)(m1 & 0xFFFE0000u)) * d1;
    float c2 = __int_as_float((int)(m2 & 0xFFFE0000u)) * d2v;
    float c3 = __int_as_float((int)(m3 & 0xFFFE0000u)) * d3;
    int ib0 = ia0 + 8, ib1 = ia1 + 8, ib2 = ia2 + 8, ib3 = ia3 + 8;
    unsigned n0 = edata[ib0 < r1 ? ib0 : -64];
    unsigned n1 = edata[ib1 < r2 ? ib1 : -64];
    unsigned n2 = edata[ib2 < r3 ? ib2 : -64];
    unsigned n3 = edata[ib3 < r4 ? ib3 : -64];

    #pragma unroll 2
    for (int s = 0; s < nsteps; ++s) {
        uint2 x0 = hb[(n0 & 0x1ffffu)*8u + l];
        uint2 x1 = hb[(n1 & 0x1ffffu)*8u + l];
        uint2 x2 = hb[(n2 & 0x1ffffu)*8u + l];
        uint2 x3 = hb[(n3 & 0x1ffffu)*8u + l];
        float e0 = __int_as_float((int)(n0 & 0xFFFE0000u)) * d0;
        float e1 = __int_as_float((int)(n1 & 0xFFFE0000u)) * d1;
        float e2 = __int_as_float((int)(n2 & 0xFFFE0000u)) * d2v;
        float e3 = __int_as_float((int)(n3 & 0xFFFE0000u)) * d3;
        ib0 += 8; ib1 += 8; ib2 += 8; ib3 += 8;
        n0 = edata[ib0 < r1 ? ib0 : -64];
        n1 = edata[ib1 < r2 ? ib1 : -64];
        n2 = edata[ib2 < r3 ? ib2 : -64];
        n3 = edata[ib3 < r4 ? ib3 : -64];
        a00 = fmaf(c0, blo(w0.x), a00); a01 = fmaf(c0, bhi(w0.x), a01);
        a02 = fmaf(c0, blo(w0.y), a02); a03 = fmaf(c0, bhi(w0.y), a03);
        a10 = fmaf(c1, blo(w1.x), a10); a11 = fmaf(c1, bhi(w1.x), a11);
        a12 = fmaf(c1, blo(w1.y), a12); a13 = fmaf(c1, bhi(w1.y), a13);
        a20 = fmaf(c2, blo(w2.x), a20); a21 = fmaf(c2, bhi(w2.x), a21);
        a22 = fmaf(c2, blo(w2.y), a22); a23 = fmaf(c2, bhi(w2.y), a23);
        a30 = fmaf(c3, blo(w3.x), a30); a31 = fmaf(c3, bhi(w3.x), a31);
        a32 = fmaf(c3, blo(w3.y), a32); a33 = fmaf(c3, bhi(w3.y), a33);
        w0 = x0; w1 = x1; w2 = x2; w3 = x3;
        c0 = e0; c1 = e1; c2 = e2; c3 = e3;
    }

    a00 += __shfl_xor(a00, 8); a00 += __shfl_xor(a00, 16); a00 += __shfl_xor(a00, 32);
    a01 += __shfl_xor(a01, 8); a01 += __shfl_xor(a01, 16); a01 += __shfl_xor(a01, 32);
    a02 += __shfl_xor(a02, 8); a02 += __shfl_xor(a02, 16); a02 += __shfl_xor(a02, 32);
    a03 += __shfl_xor(a03, 8); a03 += __shfl_xor(a03, 16); a03 += __shfl_xor(a03, 32);
    a10 += __shfl_xor(a10, 8); a10 += __shfl_xor(a10, 16); a10 += __shfl_xor(a10, 32);
    a11 += __shfl_xor(a11, 8); a11 += __shfl_xor(a11, 16); a11 += __shfl_xor(a11, 32);
    a12 += __shfl_xor(a12, 8); a12 += __shfl_xor(a12, 16); a12 += __shfl_xor(a12, 32);
    a13 += __shfl_xor(a13, 8); a13 += __shfl_xor(a13, 16); a13 += __shfl_xor(a13, 32);
    a20 += __shfl_xor(a20, 8); a20 += __shfl_xor(a20, 16); a20 += __shfl_xor(a20, 32);
    a21 += __shfl_xor(a21, 8); a21 += __shfl_xor(a21, 16); a21 += __shfl_xor(a21, 32);
    a22 += __shfl_xor(a22, 8); a22 += __shfl_xor(a22, 16); a22 += __shfl_xor(a22, 32);
    a23 += __shfl_xor(a23, 8); a23 += __shfl_xor(a23, 16); a23 += __shfl_xor(a23, 32);
    a30 += __shfl_xor(a30, 8); a30 += __shfl_xor(a30, 16); a30 += __shfl_xor(a30, 32);
    a31 += __shfl_xor(a31, 8); a31 += __shfl_xor(a31, 16); a31 += __shfl_xor(a31, 32);
    a32 += __shfl_xor(a32, 8); a32 += __shfl_xor(a32, 16); a32 += __shfl_xor(a32, 32);
    a33 += __shfl_xor(a33, 8); a33 += __shfl_xor(a33, 16); a33 += __shfl_xor(a33, 32);

    if (g == 0) {
        const int fb = half*32 + (int)l*4;
        const float b0 = ld1(bias, fb+0, f), b1 = ld1(bias, fb+1, f);
        const float b2 = ld1(bias, fb+2, f), b3 = ld1(bias, fb+3, f);
        {   uint2 hv = hb[(size_t)(node0+0)*8 + l];
            float s0=a00+b0+d0*blo(hv.x), s1=a01+b1+d0*bhi(hv.x);
            float s2=a02+b2+d0*blo(hv.y), s3=a03+b3+d0*bhi(hv.y);
            aggB[(size_t)(node0+0)*16 + half*8 + l] = make_uint2(
                (unsigned)f2bf(s0)|((unsigned)f2bf(s1)<<16),
                (unsigned)f2bf(s2)|((unsigned)f2bf(s3)<<16)); }
        {   uint2 hv = hb[(size_t)(node0+1)*8 + l];
            float s0=a10+b0+d1*blo(hv.x), s1=a11+b1+d1*bhi(hv.x);
            float s2=a12+b2+d1*blo(hv.y), s3=a13+b3+d1*bhi(hv.y);
            aggB[(size_t)(node0+1)*16 + half*8 + l] = make_uint2(
                (unsigned)f2bf(s0)|((unsigned)f2bf(s1)<<16),
                (unsigned)f2bf(s2)|((unsigned)f2bf(s3)<<16)); }
        {   uint2 hv = hb[(size_t)(node0+2)*8 + l];
            float s0=a20+b0+d2v*blo(hv.x), s1=a21+b1+d2v*bhi(hv.x);
            float s2=a22+b2+d2v*blo(hv.y), s3=a23+b3+d2v*bhi(hv.y);
            aggB[(size_t)(node0+2)*16 + half*8 + l] = make_uint2(
                (unsigned)f2bf(s0)|((unsigned)f2bf(s1)<<16),
                (unsigned)f2bf(s2)|((unsigned)f2bf(s3)<<16)); }
        {   uint2 hv = hb[(size_t)(node0+3)*8 + l];
            float s0=a30+b0+d3*blo(hv.x), s1=a31+b1+d3*bhi(hv.x);
            float s2=a32+b2+d3*blo(hv.y), s3=a33+b3+d3*bhi(hv.y);
            aggB[(size_t)(node0+3)*16 + half*8 + l] = make_uint2(
                (unsigned)f2bf(s0)|((unsigned)f2bf(s1)<<16),
                (unsigned)f2bf(s2)|((unsigned)f2bf(s3)<<16)); }
    }
}

// ================= dense kernels (MFMA) =================

// gemm1: h[half-major] = (x @ W1) * dis.  M=100K K=128 N=64.
// Block: 4 waves x 16 rows. Wt staged transposed+swizzled bf16 in LDS.
__global__ __launch_bounds__(256) void k_gemm1m(
    const int* __restrict__ flag, const void* __restrict__ x,
    const void* __restrict__ W, const float* __restrict__ dis,
    unsigned short* __restrict__ h_out) {
    __shared__ unsigned short wt[64*128];
    const int f = flag[0];
    const int tid = threadIdx.x;
    #pragma unroll
    for (int it = 0; it < 32; ++it) {
        int idx = it*256 + tid;
        int col = idx >> 7, k = idx & 127;
        wt[sw1(col,k)] = f2bf(ld1(W, (size_t)k*64 + col, f));
    }
    __syncthreads();
    const int wv = tid >> 6, lane = tid & 63;
    const int lm = lane & 15, lk = lane >> 4;
    const int rowbase = blockIdx.x*64 + wv*16;
    int arow = rowbase + lm; if (arow >= NN) arow = NN - 1;   // clamp loads
    f32x4 ac0 = {0,0,0,0}, ac1 = {0,0,0,0}, ac2 = {0,0,0,0}, ac3 = {0,0,0,0};
    #pragma unroll
    for (int ks = 0; ks < 4; ++ks) {
        const int kofs = ks*32 + lk*8;
        U8 ua;
        if (!f) {
            ua.q = *(const uint4*)((const unsigned short*)x + (size_t)arow*128 + kofs);
            ua.q.x = scrub2(ua.q.x); ua.q.y = scrub2(ua.q.y);
            ua.q.z = scrub2(ua.q.z); ua.q.w = scrub2(ua.q.w);
        } else {
            const float4 p0 = ((const float4*)x)[((size_t)arow*128 + kofs) >> 2];
            const float4 p1 = ((const float4*)x)[(((size_t)arow*128 + kofs) >> 2) + 1];
            ua.q.x = pkf(scrubf(p0.x), scrubf(p0.y));
            ua.q.y = pkf(scrubf(p0.z), scrubf(p0.w));
            ua.q.z = pkf(scrubf(p1.x), scrubf(p1.y));
            ua.q.w = pkf(scrubf(p1.z), scrubf(p1.w));
        }
        U8 b0; b0.q = *(const uint4*)&wt[sw1(0*16 + lm, kofs)];
        U8 b1; b1.q = *(const uint4*)&wt[sw1(1*16 + lm, kofs)];
        U8 b2; b2.q = *(const uint4*)&wt[sw1(2*16 + lm, kofs)];
        U8 b3; b3.q = *(const uint4*)&wt[sw1(3*16 + lm, kofs)];
        ac0 = __builtin_amdgcn_mfma_f32_16x16x32_bf16(ua.v, b0.v, ac0, 0, 0, 0);
        ac1 = __builtin_amdgcn_mfma_f32_16x16x32_bf16(ua.v, b1.v, ac1, 0, 0, 0);
        ac2 = __builtin_amdgcn_mfma_f32_16x16x32_bf16(ua.v, b2.v, ac2, 0, 0, 0);
        ac3 = __builtin_amdgcn_mfma_f32_16x16x32_bf16(ua.v, b3.v, ac3, 0, 0, 0);
    }
    // C/D: col = lm, row = lk*4 + reg. Store half-major (scaled by dis).
    float dv[4]; int rows[4];
    #pragma unroll
    for (int r = 0; r < 4; ++r) {
        rows[r] = rowbase + lk*4 + r;
        dv[r] = (rows[r] < NN) ? dis[rows[r]] : 0.f;
    }
    #pragma unroll
    for (int n = 0; n < 4; ++n) {
        const int col = n*16 + lm;
        const int hh = col >> 5, cw = col & 31;
        const f32x4 av = (n==0) ? ac0 : (n==1) ? ac1 : (n==2) ? ac2 : ac3;
        #pragma unroll
        for (int r = 0; r < 4; ++r) {
            if (rows[r] < NN)
                h_out[((size_t)hh*NN + rows[r])*32 + cw] = f2bf(av[r] * dv[r]);
        }
    }
}

// gemm64 MFMA: y = bn(relu?(in)) @ W (+bias), BN folded into W''=sc*W and
// fold-bias sh^T*W. AGG=true: half-major out scaled by dis (bias in gather).
// AGG=false: row-major out + column stats (bias included in fold).
template<bool RELU, bool AGG>
__global__ __launch_bounds__(256) void k_gemm64m(
    const int* __restrict__ flag, const unsigned short* __restrict__ in,
    const void* __restrict__ W, const void* __restrict__ bias,
    const void* __restrict__ g, const void* __restrict__ bb,
    const float* __restrict__ insums, const float* __restrict__ dis,
    unsigned short* __restrict__ out_bf, float* __restrict__ outsums) {
    __shared__ unsigned short wt[64*64];
    __shared__ float scs[64], shs[64], fbx[64];
    __shared__ float stx[4*64], stq[4*64];
    const int f = flag[0];
    const int tid = threadIdx.x;
    if (tid < 64) {
        float mean = insums[tid] * INV_N;
        float var  = fmaxf(insums[64+tid] * INV_N - mean*mean, 0.f);
        float s = ld1(g, tid, f) * rsqrtf(var + BN_EPS);
        scs[tid] = s;
        shs[tid] = ld1(bb, tid, f) - mean*s;
    }
    __syncthreads();
    #pragma unroll
    for (int it = 0; it < 16; ++it) {
        int idx = it*256 + tid;
        int col = idx >> 6, k = idx & 63;
        wt[sw2(col,k)] = f2bf(scs[k] * ld1(W, (size_t)k*64 + col, f));
    }
    if (tid < 64) {
        float s = AGG ? 0.f : ld1(bias, tid, f);
        for (int k = 0; k < 64; ++k) s += shs[k] * ld1(W, (size_t)k*64 + tid, f);
        fbx[tid] = s;
    }
    __syncthreads();
    const int wv = tid >> 6, lane = tid & 63;
    const int lm = lane & 15, lk = lane >> 4;
    const int rowbase = blockIdx.x*64 + wv*16;
    int arow = rowbase + lm; if (arow >= NN) arow = NN - 1;
    f32x4 ac0 = {0,0,0,0}, ac1 = {0,0,0,0}, ac2 = {0,0,0,0}, ac3 = {0,0,0,0};
    #pragma unroll
    for (int ks = 0; ks < 2; ++ks) {
        const int kofs = ks*32 + lk*8;
        U8 ua;
        ua.q = *(const uint4*)(in + (size_t)arow*64 + kofs);
        if (RELU) {
            ua.q.x = relu2(ua.q.x); ua.q.y = relu2(ua.q.y);
            ua.q.z = relu2(ua.q.z); ua.q.w = relu2(ua.q.w);
        } else {
            ua.q.x = scrub2(ua.q.x); ua.q.y = scrub2(ua.q.y);
            ua.q.z = scrub2(ua.q.z); ua.q.w = scrub2(ua.q.w);
        }
        U8 b0; b0.q = *(const uint4*)&wt[sw2(0*16 + lm, kofs)];
        U8 b1; b1.q = *(const uint4*)&wt[sw2(1*16 + lm, kofs)];
        U8 b2; b2.q = *(const uint4*)&wt[sw2(2*16 + lm, kofs)];
        U8 b3; b3.q = *(const uint4*)&wt[sw2(3*16 + lm, kofs)];
        ac0 = __builtin_amdgcn_mfma_f32_16x16x32_bf16(ua.v, b0.v, ac0, 0, 0, 0);
        ac1 = __builtin_amdgcn_mfma_f32_16x16x32_bf16(ua.v, b1.v, ac1, 0, 0, 0);
        ac2 = __builtin_amdgcn_mfma_f32_16x16x32_bf16(ua.v, b2.v, ac2, 0, 0, 0);
        ac3 = __builtin_amdgcn_mfma_f32_16x16x32_bf16(ua.v, b3.v, ac3, 0, 0, 0);
    }
    float dv[4]; int rows[4];
    #pragma unroll
    for (int r = 0; r < 4; ++r) {
        rows[r] = rowbase + lk*4 + r;
        dv[r] = (AGG && rows[r] < NN) ? dis[rows[r]] : 0.f;
    }
    if (AGG) {
        #pragma unroll
        for (int n = 0; n < 4; ++n) {
            const int col = n*16 + lm;
            const int hh = col >> 5, cw = col & 31;
            const float fbc = fbx[col];
            const f32x4 av = (n==0) ? ac0 : (n==1) ? ac1 : (n==2) ? ac2 : ac3;
            #pragma unroll
            for (int r = 0; r < 4; ++r) {
                if (rows[r] < NN)
                    out_bf[((size_t)hh*NN + rows[r])*32 + cw] =
                        f2bf((av[r] + fbc) * dv[r]);
            }
        }
    } else {
        #pragma unroll
        for (int n = 0; n < 4; ++n) {
            const int col = n*16 + lm;
            const float fbc = fbx[col];
            const f32x4 av = (n==0) ? ac0 : (n==1) ? ac1 : (n==2) ? ac2 : ac3;
            float s = 0.f, q = 0.f;
            #pragma unroll
            for (int r = 0; r < 4; ++r) {
                if (rows[r] < NN) {
                    float y = av[r] + fbc;
                    out_bf[(size_t)rows[r]*64 + col] = f2bf(y);
                    s += y; q += y*y;
                }
            }
            s += __shfl_xor(s, 16); s += __shfl_xor(s, 32);
            q += __shfl_xor(q, 16); q += __shfl_xor(q, 32);
            if (lk == 0) { stx[wv*64 + col] = s; stq[wv*64 + col] = q; }
        }
        __syncthreads();
        if (tid < 64) {
            float S = stx[tid] + stx[64+tid] + stx[128+tid] + stx[192+tid];
            float Q = stq[tid] + stq[64+tid] + stq[128+tid] + stq[192+tid];
            unsafeAtomicAdd(&outsums[tid], S);
            unsafeAtomicAdd(&outsums[64+tid], Q);
        }
    }
}

// BN column stats over bf16 tensor (uint2 = 4 features); 512 blocks
__global__ __launch_bounds__(256) void k_bnstats_bf(const uint2* __restrict__ src,
                                                    float* __restrict__ sumout, int relu) {
    const int tid = threadIdx.x;
    float s0=0,s1=0,s2=0,s3=0, q0=0,q1=0,q2=0,q3=0;
    for (int g = blockIdx.x*256 + tid; g < NN*16; g += 512*256) {
        uint2 u = src[g];
        float vx = blo(u.x), vy = bhi(u.x), vz = blo(u.y), vw = bhi(u.y);
        if (relu) { vx=fmaxf(vx,0.f); vy=fmaxf(vy,0.f);
                    vz=fmaxf(vz,0.f); vw=fmaxf(vw,0.f); }
        s0+=vx; q0+=vx*vx; s1+=vy; q1+=vy*vy;
        s2+=vz; q2+=vz*vz; s3+=vw; q3+=vw*vw;
    }
    __shared__ float ls[1024], lq[1024];
    ls[tid*4+0]=s0; ls[tid*4+1]=s1; ls[tid*4+2]=s2; ls[tid*4+3]=s3;
    lq[tid*4+0]=q0; lq[tid*4+1]=q1; lq[tid*4+2]=q2; lq[tid*4+3]=q3;
    __syncthreads();
    if (tid < 64) {
        int grp = tid >> 2, k = tid & 3;
        float s = 0.f, q = 0.f;
        #pragma unroll
        for (int m = 0; m < 16; ++m) {
            int idx = (grp + 16*m)*4 + k;
            s += ls[idx]; q += lq[idx];
        }
        unsafeAtomicAdd(&sumout[tid], s);
        unsafeAtomicAdd(&sumout[64+tid], q);
    }
}

// final: out = bn3(y3_bf16) @ lin2_W + lin2_b
__global__ __launch_bounds__(256) void k_final(
    const int* __restrict__ flag, const unsigned short* __restrict__ y3,
    const void* __restrict__ g, const void* __restrict__ bb,
    const float* __restrict__ sums, const void* __restrict__ w2,
    const void* __restrict__ b2, void* __restrict__ out) {
    __shared__ __align__(16) float tile[64*64];
    __shared__ float wp[64], tv[64];
    const int f = flag[0];
    const int tid = threadIdx.x;
    const int base = blockIdx.x * 64;
    if (tid < 64) {
        float mean = sums[tid] * INV_N;
        float var  = fmaxf(sums[64+tid] * INV_N - mean*mean, 0.f);
        float s = ld1(g, tid, f) * rsqrtf(var + BN_EPS);
        float t = ld1(bb, tid, f) - mean*s;
        float w = ld1(w2, tid, f);
        wp[tid] = s*w; tv[tid] = t*w;
    }
    #pragma unroll
    for (int it = 0; it < 4; ++it) {
        int i4 = it*256 + tid;
        int row = i4 >> 4, c4 = (i4 & 15)*4;
        float4 v = make_float4(0,0,0,0);
        if (base + row < NN) {
            ushort4 u = *(const ushort4*)&y3[(size_t)(base+row)*64 + c4];
            v = make_float4(bf2f(u.x), bf2f(u.y), bf2f(u.z), bf2f(u.w));
        }
        *(float4*)&tile[row*64 + c4] = v;
    }
    __syncthreads();
    if (tid < 64 && base + tid < NN) {
        float a = ld1(b2, 0, f);
        #pragma unroll
        for (int c = 0; c < 64; ++c) a += tv[c];
        #pragma unroll
        for (int cc = 0; cc < 64; ++cc) {
            int c = (cc + tid) & 63;
            a += tile[tid*64 + c] * wp[c];
        }
        if (f) ((float*)out)[base + tid] = a;
        else   ((unsigned short*)out)[base + tid] = f2bf(a);
    }
}

extern "C" void kernel_launch(void* const* d_in, const int* in_sizes, int n_in,
                              void* d_out, int out_size, void* d_ws, size_t ws_size,
                              hipStream_t stream) {
    const unsigned short* x = (const unsigned short*)d_in[0];
    const void* ew  = d_in[1];
    const void* W1  = d_in[2];
    const void* b1  = d_in[3];
    const void* W2  = d_in[4];
    const void* b2  = d_in[5];
    const void* l1W = d_in[6];
    const void* l1b = d_in[7];
    const void* l2W = d_in[8];
    const void* l2b = d_in[9];
    const void* g1  = d_in[10];
    const void* bb1 = d_in[11];
    const void* g2  = d_in[12];
    const void* bb2 = d_in[13];
    const void* g3  = d_in[14];
    const void* bb3 = d_in[15];
    const int* eidx = (const int*)d_in[16];

    int*   flag = (int*)d_ws;
    float* wsf  = (float*)d_ws;
    float* sums = wsf + 16;
    float* dis  = wsf + 400;
    uint2*          aggB = (uint2*)(wsf + 100400);
    unsigned short* aggS = (unsigned short*)(wsf + 100400);
    unsigned short* hbuf = (unsigned short*)(wsf + 6500400);
    int*      histmat = (int*)(wsf + 9700400);
    int*      rowptr2 = histmat;
    int*      btot    = (int*)(wsf + 10500656);
    int*      bstart  = (int*)(wsf + 10502224);
    unsigned* edata   = (unsigned*)(wsf + 10503792);
    int2*     scr     = (int2*)(wsf + 100400);
    const size_t NEED = (size_t)13703792 * 4;
    if (ws_size < NEED) return;

    k_detect2  <<<1, 256, 0, stream>>>(x, eidx, flag, sums);
    k_hist     <<<NSB, 256, 0, stream>>>(flag, eidx, histmat);
    k_scanA    <<<NBK, 256, 0, stream>>>(histmat, btot);
    k_scanB    <<<1, 1024, 0, stream>>>(btot, bstart, edata);
    k_scatter  <<<NSB, 512, 0, stream>>>(flag, eidx, ew, histmat, bstart, scr);
    k_sortdeg  <<<NBK, 256, 0, stream>>>(bstart, scr, edata, rowptr2, dis);
    // layer 1
    k_gemm1m   <<<1563, 256, 0, stream>>>(flag, x, W1, dis, hbuf);
    k_gather9  <<<2*QBLK8, 256, 0, stream>>>(flag, rowptr2, edata, dis, b1,
                                             (const uint2*)hbuf, aggB);
    k_bnstats_bf<<<512, 256, 0, stream>>>((const uint2*)aggB, sums + 0, 1);
    // layer 2
    k_gemm64m<true, true><<<1563, 256, 0, stream>>>(flag, aggS, W2, b2, g1, bb1,
                                                    sums + 0, dis, hbuf, nullptr);
    k_gather9  <<<2*QBLK8, 256, 0, stream>>>(flag, rowptr2, edata, dis, b2,
                                             (const uint2*)hbuf, aggB);
    k_bnstats_bf<<<512, 256, 0, stream>>>((const uint2*)aggB, sums + 128, 0);
    // lin1 (+ bn3 stats), y3 bf16 in place over agg2
    k_gemm64m<false, false><<<1563, 256, 0, stream>>>(flag, aggS, l1W, l1b, g2, bb2,
                                                      sums + 128, dis, aggS, sums + 256);
    k_final    <<<1563, 256, 0, stream>>>(flag, aggS, g3, bb3, sums + 256, l2W, l2b, d_out);
}